// Round 3
// baseline (234.488 us; speedup 1.0000x reference)
//
#include <hip/hip_runtime.h>
#include <hip/hip_bf16.h>
#include <stdint.h>

typedef __attribute__((ext_vector_type(8))) short short8;
typedef __attribute__((ext_vector_type(8))) unsigned short ushort8;
typedef __attribute__((ext_vector_type(4))) unsigned short ushort4v;
typedef __attribute__((ext_vector_type(4))) float f32x4;
typedef __attribute__((ext_vector_type(16))) float f32x16;

#define B_ 8
#define N_ 4096
#define C_ 256
#define D_ 32
#define LOG2E 1.44269504088896f

__device__ inline unsigned short f2bf(float f) {
  union { float f; unsigned u; } v; v.f = f;
  unsigned r = v.u + 0x7fffu + ((v.u >> 16) & 1u);
  return (unsigned short)(r >> 16);
}
__device__ inline float exp2_fast(float x) {
  float r; asm("v_exp_f32 %0, %1" : "=v"(r) : "v"(x)); return r;
}
__device__ inline unsigned cvt_pk_bf16(float lo, float hi) {
  unsigned r; asm("v_cvt_pk_bf16_f32 %0, %1, %2" : "=v"(r) : "v"(lo), "v"(hi)); return r;
}
// swap: a <- [a.lanes0-31 | b.lanes0-31], b <- [a.lanes32-63 | b.lanes32-63]
__device__ inline void permlane32_swap(unsigned& a, unsigned& b) {
  asm volatile("v_permlane32_swap_b32 %0, %1" : "+v"(a), "+v"(b));
}
__device__ inline void gll16(const unsigned short* src, void* lds) {
  __builtin_amdgcn_global_load_lds((const __attribute__((address_space(1))) void*)src,
                                   (__attribute__((address_space(3))) void*)lds, 16, 0, 0);
}

// ---------------- kernel 0: weight cast+transpose ----------------
// wcomb[320][256]: rows 0-31 w_q^T * log2e | 32-63 w_k^T | 64-319 w_v^T. woT[256][256].
__global__ __launch_bounds__(256) void prep_kernel(const float* __restrict__ wq,
                                                   const float* __restrict__ wk,
                                                   const float* __restrict__ wv,
                                                   const float* __restrict__ wo,
                                                   unsigned short* __restrict__ wcomb,
                                                   unsigned short* __restrict__ woT) {
  int i = blockIdx.x * 256 + threadIdx.x;  // total 147456
  if (i < 81920) {
    int row = i >> 8, kk = i & 255;
    float v;
    if (row < 32)       v = wq[kk * 32 + row] * LOG2E;
    else if (row < 64)  v = wk[kk * 32 + (row - 32)];
    else                v = wv[kk * 256 + (row - 64)];
    wcomb[i] = f2bf(v);
  } else {
    int j = i - 81920;  // woT[c][e] = wo[e][c]
    int c = j >> 8, e = j & 255;
    woT[j] = f2bf(wo[e * 256 + c]);
  }
}

// ---------------- kernel 1: QKV projection GEMM (x read ONCE) ----------------
__global__ __launch_bounds__(256, 4) void qkv_kernel(const float* __restrict__ x,
                                                     const unsigned short* __restrict__ wcomb,
                                                     unsigned short* __restrict__ q,
                                                     unsigned short* __restrict__ k,
                                                     unsigned short* __restrict__ vT) {
  const int lane = threadIdx.x & 63, w = threadIdx.x >> 6;
  const int bx = blockIdx.x;
  const int g = lane >> 4, li = lane & 15;
  const int mt = bx * 64 + w * 16;
  const float* xrow = x + (size_t)(mt + li) * 256 + (g << 3);
  const unsigned short* wrow = wcomb + (size_t)li * 256 + (g << 3);
  f32x4 acc[20] = {};
  for (int kk = 0; kk < 256; kk += 32) {
    f32x4 a0 = *reinterpret_cast<const f32x4*>(xrow + kk);
    f32x4 a1 = *reinterpret_cast<const f32x4*>(xrow + kk + 4);
    short8 a;
    a[0] = (short)f2bf(a0[0]); a[1] = (short)f2bf(a0[1]);
    a[2] = (short)f2bf(a0[2]); a[3] = (short)f2bf(a0[3]);
    a[4] = (short)f2bf(a1[0]); a[5] = (short)f2bf(a1[1]);
    a[6] = (short)f2bf(a1[2]); a[7] = (short)f2bf(a1[3]);
#pragma unroll
    for (int ct = 0; ct < 20; ++ct) {
      short8 bb = *reinterpret_cast<const short8*>(wrow + (size_t)ct * 16 * 256 + kk);
      acc[ct] = __builtin_amdgcn_mfma_f32_16x16x32_bf16(a, bb, acc[ct], 0, 0, 0);
    }
  }
  const int bb_ = bx >> 6;
  const int nloc = (bx & 63) * 64 + w * 16 + (g << 2);
#pragma unroll
  for (int ct = 0; ct < 4; ++ct) {
    int col = ct * 16 + li;
    unsigned short* dst = (ct < 2) ? q : k;
    int cc = (ct < 2) ? col : col - 32;
#pragma unroll
    for (int r = 0; r < 4; ++r)
      dst[((size_t)bb_ * N_ + nloc + r) * D_ + cc] = f2bf(acc[ct][r]);
  }
#pragma unroll
  for (int ct = 4; ct < 20; ++ct) {
    int vcol = (ct - 4) * 16 + li;
    ushort4v pk;
    pk[0] = f2bf(acc[ct][0]); pk[1] = f2bf(acc[ct][1]);
    pk[2] = f2bf(acc[ct][2]); pk[3] = f2bf(acc[ct][3]);
    *reinterpret_cast<ushort4v*>(&vT[((size_t)bb_ * C_ + vcol) * N_ + nloc]) = pk;
  }
}

// ---------------- kernel 2: flash attention, 32x32 MFMA, P in registers ----------------
// grid 2048: b = blk&7 (XCD pin), rest>>3: qtile64 = rest&63, cslice = rest>>6.
// 4 waves: qh = w&1 (32q half), kvh = w>>1 (2048-kv half). Each wave: 64c x 32q,
// walks 64 chunks of 32 kv. K+V chunk staged cooperatively by the qh-pair; one
// __syncthreads per iter (its vmcnt(0) IS the stage-completion sync).
__global__ __launch_bounds__(256, 4) void flash_kernel(const unsigned short* __restrict__ q,
                                                       const unsigned short* __restrict__ k,
                                                       const unsigned short* __restrict__ vT,
                                                       unsigned short* __restrict__ att) {
  // per kvh (x2): V dbuf 2x4KB + K dbuf 2x2KB = 12KB -> 24KB staging; merge reuses it.
  __shared__ __align__(16) char smem[25088];
  const int tid = threadIdx.x;
  const int l = tid & 63, w = tid >> 6;
  const int qh = w & 1, kvh = w >> 1;
  const int blk = blockIdx.x;
  const int b = blk & 7;
  const int rest = blk >> 3;
  const int mq = (rest & 63) * 64;
  const int c0 = (rest >> 6) * 64;
  const int h = l >> 5, l31 = l & 31, l3 = l & 3;

  const unsigned short* kb_ = k + (size_t)b * N_ * D_;
  const unsigned short* vb_ = vT + (size_t)b * C_ * N_;

  // Q B-fragments (col=q=l&31, k=d=8h+j+16s), q row-major load
  const size_t qoff = ((size_t)b * N_ + mq + qh * 32 + l31) * D_ + 8 * h;
  const short8 qb0 = *reinterpret_cast<const short8*>(q + qoff);
  const short8 qb1 = *reinterpret_cast<const short8*>(q + qoff + 16);

  // staging source swizzle: LDS 16B-block bk holds data-block bk^(row&3)
  const int swz_src = (l3 ^ ((l >> 2) & 3)) << 3;  // elements
  const int vsrc_c0 = c0 + 16 * (qh * 2) + (l >> 2);
  const int vsrc_c1 = vsrc_c0 + 16;
  const int ksrc_r = qh * 16 + (l >> 2);

  const int R = kvh * 12288;  // this kv-group's staging region (bytes)
  // read offsets (bytes within V/K buffer): A-frag needs data-block (2s+h) at row r
  const int voff00 = l31 * 64 + (((0 + h) ^ l3) << 4);
  const int voff01 = l31 * 64 + (((2 + h) ^ l3) << 4);
  const int voff10 = voff00 + 2048, voff11 = voff01 + 2048;
  const int koff0 = l31 * 64 + (((0 + h) ^ l3) << 4);
  const int koff1 = l31 * 64 + (((2 + h) ^ l3) << 4);

  f32x16 o0 = {}, o1 = {};
  float lsum = 0.f;
  int kv0 = kvh * 2048;

  // prologue: stage chunk 0 into buf0
  gll16(vb_ + (size_t)vsrc_c0 * N_ + kv0 + swz_src, smem + R + (qh * 2) * 1024);
  gll16(vb_ + (size_t)vsrc_c1 * N_ + kv0 + swz_src, smem + R + (qh * 2 + 1) * 1024);
  gll16(kb_ + (size_t)(kv0 + ksrc_r) * D_ + swz_src, smem + R + 8192 + qh * 1024);
  __syncthreads();

  for (int i = 0; i < 64; ++i) {
    const int buf = i & 1;
    const char* vreg = smem + R + buf * 4096;
    const char* kreg = smem + R + 8192 + buf * 2048;
    short8 ka0 = *reinterpret_cast<const short8*>(kreg + koff0);
    short8 ka1 = *reinterpret_cast<const short8*>(kreg + koff1);
    short8 va00 = *reinterpret_cast<const short8*>(vreg + voff00);
    short8 va01 = *reinterpret_cast<const short8*>(vreg + voff01);
    short8 va10 = *reinterpret_cast<const short8*>(vreg + voff10);
    short8 va11 = *reinterpret_cast<const short8*>(vreg + voff11);
    if (i < 63) {  // stage next chunk into buf^1 (lands during compute+barrier)
      const int kvn = kv0 + 32;
      char* dV = smem + R + (buf ^ 1) * 4096;
      gll16(vb_ + (size_t)vsrc_c0 * N_ + kvn + swz_src, dV + (qh * 2) * 1024);
      gll16(vb_ + (size_t)vsrc_c1 * N_ + kvn + swz_src, dV + (qh * 2 + 1) * 1024);
      gll16(kb_ + (size_t)(kvn + ksrc_r) * D_ + swz_src,
            smem + R + 8192 + (buf ^ 1) * 2048 + qh * 1024);
    }
    // S^T[32kv][32q] = K . Q^T  (rows kv = (r&3)+8(r>>2)+4h, col q = l31)
    f32x16 z = {};
    f32x16 s = __builtin_amdgcn_mfma_f32_32x32x16_bf16(ka0, qb0, z, 0, 0, 0);
    s = __builtin_amdgcn_mfma_f32_32x32x16_bf16(ka1, qb1, s, 0, 0, 0);
    float p[16];
#pragma unroll
    for (int r = 0; r < 16; ++r) p[r] = exp2_fast(s[r]);
    lsum += (((p[0] + p[1]) + (p[2] + p[3])) + ((p[4] + p[5]) + (p[6] + p[7]))) +
            (((p[8] + p[9]) + (p[10] + p[11])) + ((p[12] + p[13]) + (p[14] + p[15])));
    // pack P^T into PV B-fragments: 8 cvt_pk + 4 permlane32_swap
    unsigned x0 = cvt_pk_bf16(p[0], p[1]),   y0 = cvt_pk_bf16(p[4], p[5]);
    unsigned x1 = cvt_pk_bf16(p[2], p[3]),   y1 = cvt_pk_bf16(p[6], p[7]);
    unsigned x2 = cvt_pk_bf16(p[8], p[9]),   y2 = cvt_pk_bf16(p[12], p[13]);
    unsigned x3 = cvt_pk_bf16(p[10], p[11]), y3 = cvt_pk_bf16(p[14], p[15]);
    permlane32_swap(x0, y0); permlane32_swap(x1, y1);
    permlane32_swap(x2, y2); permlane32_swap(x3, y3);
    union U { unsigned u[4]; short8 v; };
    U pf0; pf0.u[0] = x0; pf0.u[1] = x1; pf0.u[2] = y0; pf0.u[3] = y1;  // kv 0-15
    U pf1; pf1.u[0] = x2; pf1.u[1] = x3; pf1.u[2] = y2; pf1.u[3] = y3;  // kv 16-31
    // O^T[64c][32q] += V^T . P^T
    o0 = __builtin_amdgcn_mfma_f32_32x32x16_bf16(va00, pf0.v, o0, 0, 0, 0);
    o0 = __builtin_amdgcn_mfma_f32_32x32x16_bf16(va01, pf1.v, o0, 0, 0, 0);
    o1 = __builtin_amdgcn_mfma_f32_32x32x16_bf16(va10, pf0.v, o1, 0, 0, 0);
    o1 = __builtin_amdgcn_mfma_f32_32x32x16_bf16(va11, pf1.v, o1, 0, 0, 0);
    kv0 += 32;
    __syncthreads();  // readers done with buf; partner's next-stage landed (vmcnt0)
  }

  // ---- merge kv halves (fixed m=0: partials just add), normalize, store ----
  lsum += __shfl_xor(lsum, 32);  // combine h-halves: all lanes hold full sum for q=l31
  float* fs = reinterpret_cast<float*>(smem);
  if (kvh == 1) {
#pragma unroll
    for (int v = 0; v < 4; ++v) {
      f32x4 t; t[0] = o0[v * 4]; t[1] = o0[v * 4 + 1]; t[2] = o0[v * 4 + 2]; t[3] = o0[v * 4 + 3];
      *reinterpret_cast<f32x4*>(smem + qh * 8192 + l * 128 + ((v ^ (l & 7)) << 4)) = t;
    }
#pragma unroll
    for (int v = 4; v < 8; ++v) {
      f32x4 t; t[0] = o1[(v - 4) * 4]; t[1] = o1[(v - 4) * 4 + 1];
      t[2] = o1[(v - 4) * 4 + 2]; t[3] = o1[(v - 4) * 4 + 3];
      *reinterpret_cast<f32x4*>(smem + qh * 8192 + l * 128 + ((v ^ (l & 7)) << 4)) = t;
    }
    fs[6144 + qh * 64 + l] = lsum;
  }
  __syncthreads();
  if (kvh == 0) {
    const float inv = 1.0f / (lsum + fs[6144 + qh * 64 + l]);
#pragma unroll
    for (int v = 0; v < 4; ++v) {
      f32x4 t = *reinterpret_cast<const f32x4*>(smem + qh * 8192 + l * 128 + ((v ^ (l & 7)) << 4));
      o0[v * 4] += t[0]; o0[v * 4 + 1] += t[1]; o0[v * 4 + 2] += t[2]; o0[v * 4 + 3] += t[3];
    }
#pragma unroll
    for (int v = 4; v < 8; ++v) {
      f32x4 t = *reinterpret_cast<const f32x4*>(smem + qh * 8192 + l * 128 + ((v ^ (l & 7)) << 4));
      o1[(v - 4) * 4] += t[0]; o1[(v - 4) * 4 + 1] += t[1];
      o1[(v - 4) * 4 + 2] += t[2]; o1[(v - 4) * 4 + 3] += t[3];
    }
    const size_t rowoff = ((size_t)b * N_ + mq + qh * 32 + l31) * C_;
#pragma unroll
    for (int j = 0; j < 8; ++j) {
      const int c = c0 + 2 * (j & 1) + 8 * (j >> 1) + 4 * h;
      unsigned w0 = cvt_pk_bf16(o0[2 * j] * inv, o0[2 * j + 1] * inv);
      *reinterpret_cast<unsigned*>(&att[rowoff + c]) = w0;
      unsigned w1 = cvt_pk_bf16(o1[2 * j] * inv, o1[2 * j + 1] * inv);
      *reinterpret_cast<unsigned*>(&att[rowoff + 32 + c]) = w1;
    }
  }
}

// ---------------- kernel 3: output projection + residual (att read ONCE) ----------------
__global__ __launch_bounds__(256, 4) void out_kernel(const unsigned short* __restrict__ att,
                                                     const unsigned short* __restrict__ woT,
                                                     const float* __restrict__ x,
                                                     float* __restrict__ out) {
  const int lane = threadIdx.x & 63, w = threadIdx.x >> 6;
  const int bx = blockIdx.x;
  const int g = lane >> 4, li = lane & 15;
  const int m0 = bx * 64 + w * 16;
  const unsigned short* arow = att + (size_t)(m0 + li) * 256 + (g << 3);
  const unsigned short* wrow = woT + (size_t)li * 256 + (g << 3);
  f32x4 acc[16] = {};
  for (int kk = 0; kk < 256; kk += 32) {
    short8 a = *reinterpret_cast<const short8*>(arow + kk);
#pragma unroll
    for (int ct = 0; ct < 16; ++ct) {
      short8 bb = *reinterpret_cast<const short8*>(wrow + (size_t)ct * 16 * 256 + kk);
      acc[ct] = __builtin_amdgcn_mfma_f32_16x16x32_bf16(a, bb, acc[ct], 0, 0, 0);
    }
  }
#pragma unroll
  for (int ct = 0; ct < 16; ++ct) {
    int col = ct * 16 + li;
#pragma unroll
    for (int r = 0; r < 4; ++r) {
      size_t idx = (size_t)(m0 + (g << 2) + r) * 256 + col;
      out[idx] = acc[ct][r] + x[idx];
    }
  }
}

extern "C" void kernel_launch(void* const* d_in, const int* in_sizes, int n_in,
                              void* d_out, int out_size, void* d_ws, size_t ws_size,
                              hipStream_t stream) {
  const float* x  = (const float*)d_in[0];
  const float* wq = (const float*)d_in[1];
  const float* wk = (const float*)d_in[2];
  const float* wv = (const float*)d_in[3];
  const float* wo = (const float*)d_in[4];
  float* out = (float*)d_out;
  char* ws = (char*)d_ws;
  unsigned short* wcomb = (unsigned short*)(ws + 0);         // 163840 B
  unsigned short* woT   = (unsigned short*)(ws + 163840);    // 131072 B
  unsigned short* q     = (unsigned short*)(ws + 294912);    // 2 MB
  unsigned short* k     = (unsigned short*)(ws + 2392064);   // 2 MB
  unsigned short* vT    = (unsigned short*)(ws + 4489216);   // 16 MB
  unsigned short* att   = (unsigned short*)(ws + 21266432);  // 16 MB (total ~36.3 MB)

  prep_kernel<<<576, 256, 0, stream>>>(wq, wk, wv, wo, wcomb, woT);
  qkv_kernel<<<512, 256, 0, stream>>>(x, wcomb, q, k, vT);
  flash_kernel<<<2048, 256, 0, stream>>>(q, k, vT, att);
  out_kernel<<<512, 256, 0, stream>>>(att, woT, x, out);
}

// Round 4
// 192.188 us; speedup vs baseline: 1.2201x; 1.2201x over previous
//
#include <hip/hip_runtime.h>
#include <hip/hip_bf16.h>
#include <stdint.h>

typedef __attribute__((ext_vector_type(8))) short short8;
typedef __attribute__((ext_vector_type(8))) unsigned short ushort8;
typedef __attribute__((ext_vector_type(4))) unsigned short ushort4v;
typedef __attribute__((ext_vector_type(4))) float f32x4;
typedef __attribute__((ext_vector_type(16))) float f32x16;

#define B_ 8
#define N_ 4096
#define C_ 256
#define D_ 32
#define LOG2E 1.44269504088896f

__device__ inline unsigned short f2bf(float f) {
  union { float f; unsigned u; } v; v.f = f;
  unsigned r = v.u + 0x7fffu + ((v.u >> 16) & 1u);
  return (unsigned short)(r >> 16);
}
__device__ inline float bf2f(unsigned short u) {
  return __uint_as_float(((unsigned)u) << 16);
}
__device__ inline float exp2_fast(float x) {
  float r; asm("v_exp_f32 %0, %1" : "=v"(r) : "v"(x)); return r;
}
__device__ inline unsigned cvt_pk_bf16(float lo, float hi) {
  unsigned r; asm("v_cvt_pk_bf16_f32 %0, %1, %2" : "=v"(r) : "v"(lo), "v"(hi)); return r;
}
// a <- [a.l0-31 | b.l0-31], b <- [a.l32-63 | b.l32-63]
__device__ inline void permlane32_swap(unsigned& a, unsigned& b) {
  asm volatile("v_permlane32_swap_b32 %0, %1" : "+v"(a), "+v"(b));
}
__device__ inline void gll16(const unsigned short* src, void* lds) {
  __builtin_amdgcn_global_load_lds((const __attribute__((address_space(1))) void*)src,
                                   (__attribute__((address_space(3))) void*)lds, 16, 0, 0);
}

// ---------------- kernel 0: weight cast+transpose ----------------
// wcomb[320][256]: rows 0-31 w_q^T*log2e | 32-63 w_k^T | 64-319 w_v^T. woT[256][256].
__global__ __launch_bounds__(256) void prep_kernel(const float* __restrict__ wq,
                                                   const float* __restrict__ wk,
                                                   const float* __restrict__ wv,
                                                   const float* __restrict__ wo,
                                                   unsigned short* __restrict__ wcomb,
                                                   unsigned short* __restrict__ woT) {
  int i = blockIdx.x * 256 + threadIdx.x;  // total 147456
  if (i < 81920) {
    int row = i >> 8, kk = i & 255;
    float v;
    if (row < 32)       v = wq[kk * 32 + row] * LOG2E;
    else if (row < 64)  v = wk[kk * 32 + (row - 32)];
    else                v = wv[kk * 256 + (row - 64)];
    wcomb[i] = f2bf(v);
  } else {
    int j = i - 81920;  // woT[c][e] = wo[e][c]
    int c = j >> 8, e = j & 255;
    woT[j] = f2bf(wo[e * 256 + c]);
  }
}

// ---------------- kernel 1: QKV projection GEMM (x read ONCE) ----------------
__global__ __launch_bounds__(256, 4) void qkv_kernel(const float* __restrict__ x,
                                                     const unsigned short* __restrict__ wcomb,
                                                     unsigned short* __restrict__ q,
                                                     unsigned short* __restrict__ k,
                                                     unsigned short* __restrict__ vT) {
  const int lane = threadIdx.x & 63, w = threadIdx.x >> 6;
  const int bx = blockIdx.x;
  const int g = lane >> 4, li = lane & 15;
  const int mt = bx * 64 + w * 16;
  const float* xrow = x + (size_t)(mt + li) * 256 + (g << 3);
  const unsigned short* wrow = wcomb + (size_t)li * 256 + (g << 3);
  f32x4 acc[20] = {};
  for (int kk = 0; kk < 256; kk += 32) {
    f32x4 a0 = *reinterpret_cast<const f32x4*>(xrow + kk);
    f32x4 a1 = *reinterpret_cast<const f32x4*>(xrow + kk + 4);
    short8 a;
    a[0] = (short)f2bf(a0[0]); a[1] = (short)f2bf(a0[1]);
    a[2] = (short)f2bf(a0[2]); a[3] = (short)f2bf(a0[3]);
    a[4] = (short)f2bf(a1[0]); a[5] = (short)f2bf(a1[1]);
    a[6] = (short)f2bf(a1[2]); a[7] = (short)f2bf(a1[3]);
#pragma unroll
    for (int ct = 0; ct < 20; ++ct) {
      short8 bb = *reinterpret_cast<const short8*>(wrow + (size_t)ct * 16 * 256 + kk);
      acc[ct] = __builtin_amdgcn_mfma_f32_16x16x32_bf16(a, bb, acc[ct], 0, 0, 0);
    }
  }
  const int bb_ = bx >> 6;
  const int nloc = (bx & 63) * 64 + w * 16 + (g << 2);
#pragma unroll
  for (int ct = 0; ct < 4; ++ct) {
    int col = ct * 16 + li;
    unsigned short* dst = (ct < 2) ? q : k;
    int cc = (ct < 2) ? col : col - 32;
#pragma unroll
    for (int r = 0; r < 4; ++r)
      dst[((size_t)bb_ * N_ + nloc + r) * D_ + cc] = f2bf(acc[ct][r]);
  }
#pragma unroll
  for (int ct = 4; ct < 20; ++ct) {
    int vcol = (ct - 4) * 16 + li;
    ushort4v pk;
    pk[0] = f2bf(acc[ct][0]); pk[1] = f2bf(acc[ct][1]);
    pk[2] = f2bf(acc[ct][2]); pk[3] = f2bf(acc[ct][3]);
    *reinterpret_cast<ushort4v*>(&vT[((size_t)bb_ * C_ + vcol) * N_ + nloc]) = pk;
  }
}

// ---------------- kernel 2: flash attention ----------------
// grid 512: blk = qt*16 + b*2 + kvh  (same (b,kvh) -> same XCD via blk%8).
// Block: 128q x 256c, kv range = kvh*2048..+2048 in 32 chunks of 64.
// 4 waves: qg = w>>1 (64q group), ch = w&1 (128c half). Wave: 64q x 128c,
// P in registers (swapped S^T = K.Q^T, fixed m=0), acc = 8 x f32x16.
// K/V chunk staged cooperatively (global_load_lds, phase-clean XOR swizzle),
// double-buffered, ONE barrier per chunk. Unnormalized bf16 O partial + f32
// lsum partial written per kvh; merged in out_kernel.
__global__ __launch_bounds__(256, 2) void flash_kernel(const unsigned short* __restrict__ q,
                                                       const unsigned short* __restrict__ k,
                                                       const unsigned short* __restrict__ vT,
                                                       unsigned short* __restrict__ opart,
                                                       float* __restrict__ lsumpart) {
  __shared__ __align__(16) char smem[73728];  // V 2x32KB | K 2x4KB
  const int tid = threadIdx.x;
  const int l = tid & 63, w = tid >> 6;
  const int qg = w >> 1, ch = w & 1;
  const int blk = blockIdx.x;
  const int kvh = blk & 1, b = (blk >> 1) & 7, qt = blk >> 4;
  const int h = l >> 5, l31 = l & 31;

  const unsigned short* kb_ = k + (size_t)b * N_ * D_;
  const unsigned short* vb_ = vT + (size_t)b * C_ * N_;

  // Q B-frags: qb[qt2][ks]: col q = l31, k = ks*16 + 8h + j
  const size_t qbase = ((size_t)b * N_ + qt * 128 + qg * 64 + l31) * D_ + h * 8;
  short8 qb[2][2];
#pragma unroll
  for (int qt2 = 0; qt2 < 2; ++qt2)
#pragma unroll
    for (int ks = 0; ks < 2; ++ks)
      qb[qt2][ks] = *reinterpret_cast<const short8*>(q + qbase + qt2 * 32 * D_ + ks * 16);

  // staging source offsets (inverse of LDS read swizzle)
  const int vsrc_c = w * 64 + (l >> 3);                    // + t*8
  const int vsrc_boff = (((l & 7) ^ ((l >> 3) & 7)) << 3); // elements
  const int ksrc_r = w * 16 + (l >> 2);
  const int ksrc_boff = (((l & 3) ^ ((l >> 3) & 3)) << 3);

#define STAGE(BUF, KV0)                                                             \
  {                                                                                 \
    char* vdst = smem + (BUF)*32768 + w * 8192;                                     \
    _Pragma("unroll") for (int t = 0; t < 8; ++t)                                   \
        gll16(vb_ + (size_t)(vsrc_c + t * 8) * N_ + (KV0) + vsrc_boff,              \
              vdst + t * 1024);                                                     \
    gll16(kb_ + (size_t)((KV0) + ksrc_r) * D_ + ksrc_boff,                          \
          smem + 65536 + (BUF)*4096 + w * 1024);                                    \
  }

  f32x16 o[4][2] = {};  // [ct][qt2]: O^T tile (32c x 32q)
  float lsum[2] = {0.f, 0.f};
  const f32x16 z16 = {};
  int kvc = kvh * 2048;

  STAGE(0, kvc)
  __syncthreads();

  for (int i = 0; i < 32; ++i) {
    const int buf = i & 1;
    if (i < 31) STAGE(buf ^ 1, kvc + 64)
    const char* vbuf = smem + buf * 32768;
    const char* kbuf = smem + 65536 + buf * 4096;
#pragma unroll
    for (int kvt = 0; kvt < 2; ++kvt) {
      // K A-frags: row kv = kvt*32+l31, d-block b = ks*2+h, pos = b ^ ((kv>>1)&3)
      const int krow = (kvt * 32 + l31) * 64;
      const int kt = (l31 >> 1) & 3;
      short8 ka0 = *reinterpret_cast<const short8*>(kbuf + krow + (((0 + h) ^ kt) << 4));
      short8 ka1 = *reinterpret_cast<const short8*>(kbuf + krow + (((2 + h) ^ kt) << 4));
      short8 pf[2][2];
#pragma unroll
      for (int qt2 = 0; qt2 < 2; ++qt2) {
        f32x16 s = __builtin_amdgcn_mfma_f32_32x32x16_bf16(ka0, qb[qt2][0], z16, 0, 0, 0);
        s = __builtin_amdgcn_mfma_f32_32x32x16_bf16(ka1, qb[qt2][1], s, 0, 0, 0);
        float p[16];
#pragma unroll
        for (int r = 0; r < 16; ++r) p[r] = exp2_fast(s[r]);
        lsum[qt2] += (((p[0] + p[1]) + (p[2] + p[3])) + ((p[4] + p[5]) + (p[6] + p[7]))) +
                     (((p[8] + p[9]) + (p[10] + p[11])) + ((p[12] + p[13]) + (p[14] + p[15])));
        unsigned x0 = cvt_pk_bf16(p[0], p[1]),   y0 = cvt_pk_bf16(p[4], p[5]);
        unsigned x1 = cvt_pk_bf16(p[2], p[3]),   y1 = cvt_pk_bf16(p[6], p[7]);
        unsigned x2 = cvt_pk_bf16(p[8], p[9]),   y2 = cvt_pk_bf16(p[12], p[13]);
        unsigned x3 = cvt_pk_bf16(p[10], p[11]), y3 = cvt_pk_bf16(p[14], p[15]);
        permlane32_swap(x0, y0); permlane32_swap(x1, y1);
        permlane32_swap(x2, y2); permlane32_swap(x3, y3);
        union U { unsigned u[4]; short8 v; };
        U u0; u0.u[0] = x0; u0.u[1] = x1; u0.u[2] = y0; u0.u[3] = y1;
        U u1; u1.u[0] = x2; u1.u[1] = x3; u1.u[2] = y2; u1.u[3] = y3;
        pf[qt2][0] = u0.v; pf[qt2][1] = u1.v;
      }
      // PV: O^T[c][q] += V^T . P^T  (V rows 128B: pos = b ^ (c&7))
      __builtin_amdgcn_s_setprio(1);
#pragma unroll
      for (int ct = 0; ct < 4; ++ct) {
        const int crow = (ch * 128 + ct * 32 + l31) * 128;
        const int vt = l31 & 7;
        short8 va0 = *reinterpret_cast<const short8*>(
            vbuf + crow + ((((kvt * 2 + 0) * 2 + h) ^ vt) << 4));
        short8 va1 = *reinterpret_cast<const short8*>(
            vbuf + crow + ((((kvt * 2 + 1) * 2 + h) ^ vt) << 4));
        o[ct][0] = __builtin_amdgcn_mfma_f32_32x32x16_bf16(va0, pf[0][0], o[ct][0], 0, 0, 0);
        o[ct][0] = __builtin_amdgcn_mfma_f32_32x32x16_bf16(va1, pf[0][1], o[ct][0], 0, 0, 0);
        o[ct][1] = __builtin_amdgcn_mfma_f32_32x32x16_bf16(va0, pf[1][0], o[ct][1], 0, 0, 0);
        o[ct][1] = __builtin_amdgcn_mfma_f32_32x32x16_bf16(va1, pf[1][1], o[ct][1], 0, 0, 0);
      }
      __builtin_amdgcn_s_setprio(0);
    }
    kvc += 64;
    __syncthreads();  // all reads of buf done; next stage (issued at top) drained
  }

  // ---- epilogue: write unnormalized O partial (bf16) + lsum partial (f32) ----
  lsum[0] += __shfl_xor(lsum[0], 32);
  lsum[1] += __shfl_xor(lsum[1], 32);
  unsigned short* op = opart + (size_t)kvh * B_ * N_ * C_;
#pragma unroll
  for (int qt2 = 0; qt2 < 2; ++qt2) {
    const size_t rowoff =
        ((size_t)b * N_ + qt * 128 + qg * 64 + qt2 * 32 + l31) * C_ + ch * 128;
#pragma unroll
    for (int ct = 0; ct < 4; ++ct)
#pragma unroll
      for (int j = 0; j < 8; ++j) {
        const int c = ct * 32 + 2 * (j & 1) + 8 * (j >> 1) + 4 * h;
        unsigned wv = cvt_pk_bf16(o[ct][qt2][2 * j], o[ct][qt2][2 * j + 1]);
        *reinterpret_cast<unsigned*>(&op[rowoff + c]) = wv;
      }
  }
  if (ch == 0 && h == 0) {
    float* lp = lsumpart + (size_t)kvh * B_ * N_ + b * N_ + qt * 128 + qg * 64;
    lp[l31] = lsum[0];
    lp[32 + l31] = lsum[1];
  }
#undef STAGE
}

// ---------------- kernel 3: merge partials + output projection + residual ----------------
__global__ __launch_bounds__(256, 4) void out_kernel(const unsigned short* __restrict__ opart,
                                                     const float* __restrict__ lsumpart,
                                                     const unsigned short* __restrict__ woT,
                                                     const float* __restrict__ x,
                                                     float* __restrict__ out) {
  const int lane = threadIdx.x & 63, w = threadIdx.x >> 6;
  const int bx = blockIdx.x;
  const int g = lane >> 4, li = lane & 15;
  const int m0 = bx * 64 + w * 16;
  const int m = m0 + li;
  const float inv = 1.0f / (lsumpart[m] + lsumpart[B_ * N_ + m]);
  const unsigned short* arow0 = opart + (size_t)m * 256 + (g << 3);
  const unsigned short* arow1 = arow0 + (size_t)B_ * N_ * C_;
  const unsigned short* wrow = woT + (size_t)li * 256 + (g << 3);
  f32x4 acc[16] = {};
  for (int kk = 0; kk < 256; kk += 32) {
    ushort8 a0 = *reinterpret_cast<const ushort8*>(arow0 + kk);
    ushort8 a1 = *reinterpret_cast<const ushort8*>(arow1 + kk);
    short8 a;
#pragma unroll
    for (int e = 0; e < 8; ++e)
      a[e] = (short)f2bf((bf2f(a0[e]) + bf2f(a1[e])) * inv);
#pragma unroll
    for (int ct = 0; ct < 16; ++ct) {
      short8 bb = *reinterpret_cast<const short8*>(wrow + (size_t)ct * 16 * 256 + kk);
      acc[ct] = __builtin_amdgcn_mfma_f32_16x16x32_bf16(a, bb, acc[ct], 0, 0, 0);
    }
  }
#pragma unroll
  for (int ct = 0; ct < 16; ++ct) {
    int col = ct * 16 + li;
#pragma unroll
    for (int r = 0; r < 4; ++r) {
      size_t idx = (size_t)(m0 + (g << 2) + r) * 256 + col;
      out[idx] = acc[ct][r] + x[idx];
    }
  }
}

extern "C" void kernel_launch(void* const* d_in, const int* in_sizes, int n_in,
                              void* d_out, int out_size, void* d_ws, size_t ws_size,
                              hipStream_t stream) {
  const float* x  = (const float*)d_in[0];
  const float* wq = (const float*)d_in[1];
  const float* wk = (const float*)d_in[2];
  const float* wv = (const float*)d_in[3];
  const float* wo = (const float*)d_in[4];
  float* out = (float*)d_out;
  char* ws = (char*)d_ws;
  unsigned short* wcomb = (unsigned short*)(ws + 0);          // 163840 B
  unsigned short* woT   = (unsigned short*)(ws + 163840);     // 131072 B
  unsigned short* q     = (unsigned short*)(ws + 294912);     // 2 MB
  unsigned short* k     = (unsigned short*)(ws + 2392064);    // 2 MB
  unsigned short* vT    = (unsigned short*)(ws + 4489216);    // 16 MB
  unsigned short* opart = (unsigned short*)(ws + 21266432);   // 32 MB (2 parts)
  float*          lsump = (float*)(ws + 54820864);            // 256 KB (total ~52.5 MB)

  prep_kernel<<<576, 256, 0, stream>>>(wq, wk, wv, wo, wcomb, woT);
  qkv_kernel<<<512, 256, 0, stream>>>(x, wcomb, q, k, vT);
  flash_kernel<<<512, 256, 0, stream>>>(q, k, vT, opart, lsump);
  out_kernel<<<512, 256, 0, stream>>>(opart, lsump, woT, x, out);
}